// Round 5
// baseline (604.047 us; speedup 1.0000x reference)
//
#include <hip/hip_runtime.h>
#include <hip/hip_bf16.h>

#define B_ 4
#define C_ 512
#define H_ 96
#define W_ 320
#define D_ 48
#define HW_ (H_*W_)

#define KC 32              // channels per chunk = MFMA K
#define NCHUNK (C_/KC)     // 16
#define NT 320             // 5 waves; grid 768 = 3 blocks/CU exactly
#define EPS 168            // epilogue row stride in floats

typedef __attribute__((ext_vector_type(8))) short bf16x8;
typedef __attribute__((ext_vector_type(4))) float f32x4;

__device__ __forceinline__ unsigned cvt2(float lo, float hi) {
  union { __hip_bfloat162 h2; unsigned u; } u;
  u.h2 = __float22bfloat162_rn(make_float2(lo, hi));   // v_cvt_pk_bf16_f32 (RNE)
  return u.u;
}

// issue 8 global_load_dword: 16-lane groups read 64B contiguous (frag cols
// are 16-aligned 16-col tiles -> full line utilization)
#define LOADF(dst, p) do { \
  _Pragma("unroll") for (int j = 0; j < 8; ++j) dst[j] = (p)[voff[j]]; } while (0)

#define PACKF(fr, src) do { union { unsigned u[4]; bf16x8 v; } _u; \
  _u.u[0] = cvt2(src[0], src[1]); _u.u[1] = cvt2(src[2], src[3]); \
  _u.u[2] = cvt2(src[4], src[5]); _u.u[3] = cvt2(src[6], src[7]); fr = _u.v; } while (0)

__global__ __launch_bounds__(NT, 4)   // cap VGPR at 128 -> 4 waves/SIMD
void cost_volume_mfma(const float* __restrict__ Lp,
                      const float* __restrict__ Rp,
                      float* __restrict__ out) {
  __shared__ float ep[D_ * EPS];       // 32256 B, epilogue transpose only
  const int tid = threadIdx.x;
  const int bid = blockIdx.x;
  const int half = bid & 1;
  const int bh = bid >> 1;
  const int b = bh / H_, h = bh % H_;
  const int wv = __builtin_amdgcn_readfirstlane(tid >> 6);  // force SGPR bases
  const int lc = tid & 15;             // fragment row/col lane index
  const int lg = (tid >> 4) & 3;       // fragment k-granule
  const int mh0 = 2 * wv;
  const int m0 = 10 * half + mh0;      // global m-tile of ml=0

  // lane element-offsets, shared by every fragment (k = 8*lg + j)
  int voff[8];
#pragma unroll
  for (int j = 0; j < 8; ++j) voff[j] = (8 * lg + j) * HW_ + lc;

  // uniform per-fragment base pointers; fN has jn = m0+1-N
  const size_t ro = ((size_t)b * C_) * HW_ + (size_t)h * W_;
  const float* pA0 = Lp + ro + 16 * (m0 + 0);
  const float* pA1 = Lp + ro + 16 * (m0 + 1);
  const float* pB0 = Rp + ro + 16 * (m0 + 1);
  const float* pB1 = Rp + ro + 16 * (m0 + 0);
  const float* pB2 = Rp + ro + 16 * (m0 - 1 >= 0 ? m0 - 1 : 0);
  const float* pB3 = Rp + ro + 16 * (m0 - 2 >= 0 ? m0 - 2 : 0);
  const float* pB4 = Rp + ro + 16 * (m0 - 3 >= 0 ? m0 - 3 : 0);
  const bool v2 = (m0 - 1) >= 0;
  const bool v3 = (m0 - 2) >= 0;
  const bool v4 = (m0 - 3) >= 0;

  f32x4 acc[2][4];
#pragma unroll
  for (int ml = 0; ml < 2; ++ml)
#pragma unroll
    for (int dn = 0; dn < 4; ++dn) acc[ml][dn] = (f32x4){0.f, 0.f, 0.f, 0.f};

  bf16x8 f2 = {0,0,0,0,0,0,0,0}, f3 = f2, f4 = f2;   // defined even when invalid

  for (int k = 0; k < NCHUNK; ++k) {
    float ra0[8], ra1[8], rb0[8], rb1[8], rb2[8], rb3[8], rb4[8];
    // issue ALL loads first -> deep per-wave memory queue, no barrier anywhere
    LOADF(ra0, pA0); LOADF(ra1, pA1);
    LOADF(rb0, pB0); LOADF(rb1, pB1);
    if (v2) LOADF(rb2, pB2);
    if (v3) LOADF(rb3, pB3);
    if (v4) LOADF(rb4, pB4);

    bf16x8 a0, a1, f0, f1;
    PACKF(a0, ra0); PACKF(a1, ra1);
    PACKF(f0, rb0); PACKF(f1, rb1);
    if (v2) PACKF(f2, rb2);
    if (v3) PACKF(f3, rb3);
    if (v4) PACKF(f4, rb4);

    // acc[ml][dn] <-> jm = m0+ml, jn = jm-dn
    acc[0][0] = __builtin_amdgcn_mfma_f32_16x16x32_bf16(a0, f1, acc[0][0], 0, 0, 0);
    acc[1][0] = __builtin_amdgcn_mfma_f32_16x16x32_bf16(a1, f0, acc[1][0], 0, 0, 0);
    acc[1][1] = __builtin_amdgcn_mfma_f32_16x16x32_bf16(a1, f1, acc[1][1], 0, 0, 0);
    if (v2) {
      acc[0][1] = __builtin_amdgcn_mfma_f32_16x16x32_bf16(a0, f2, acc[0][1], 0, 0, 0);
      acc[1][2] = __builtin_amdgcn_mfma_f32_16x16x32_bf16(a1, f2, acc[1][2], 0, 0, 0);
    }
    if (v3) {
      acc[0][2] = __builtin_amdgcn_mfma_f32_16x16x32_bf16(a0, f3, acc[0][2], 0, 0, 0);
      acc[1][3] = __builtin_amdgcn_mfma_f32_16x16x32_bf16(a1, f3, acc[1][3], 0, 0, 0);
    }
    if (v4)
      acc[0][3] = __builtin_amdgcn_mfma_f32_16x16x32_bf16(a0, f4, acc[0][3], 0, 0, 0);

    pA0 += (size_t)KC * HW_; pA1 += (size_t)KC * HW_;
    pB0 += (size_t)KC * HW_; pB1 += (size_t)KC * HW_;
    pB2 += (size_t)KC * HW_; pB3 += (size_t)KC * HW_;
    pB4 += (size_t)KC * HW_;
  }

  // ---- epilogue: transpose through LDS -> coalesced stores ----
  __syncthreads();   // no-op ordering start (waves arrive async)
  // zero ep
#pragma unroll
  for (int e = 0; e < (D_ * EPS + NT - 1) / NT; ++e) {
    const int i = tid + NT * e;
    if (i < D_ * EPS) ep[i] = 0.f;
  }
  __syncthreads();
  const float scale = 1.f / 512.f;
#pragma unroll
  for (int ml = 0; ml < 2; ++ml) {
    const int mh = mh0 + ml;
#pragma unroll
    for (int dn = 0; dn < 4; ++dn) {
      const int jn = m0 + ml - dn;
      if (jn >= 0) {
#pragma unroll
        for (int q = 0; q < 4; ++q) {
          const int i = 4 * lg + q;          // C/D row = 4*(lane>>4) + reg
          const int d = 16 * dn + i - lc;    // d = w - w'
          if (d >= 0 && d < D_)
            ep[d * EPS + 16 * mh + i] = acc[ml][dn][q] * scale;
        }
      }
    }
  }
  __syncthreads();
  // 48 rows x 40 float4 = 1920 units = 6 per thread, coalesced stores
#pragma unroll
  for (int e = 0; e < 6; ++e) {
    const int u = tid + NT * e;
    const int d = u / 40, c4 = u % 40;
    const float4 v = *(const float4*)(ep + d * EPS + 4 * c4);
    float* o = out + (((size_t)b * D_ + d) * H_ + h) * W_ + 160 * half + 4 * c4;
    *(float4*)o = v;
  }
}

extern "C" void kernel_launch(void* const* d_in, const int* in_sizes, int n_in,
                              void* d_out, int out_size, void* d_ws, size_t ws_size,
                              hipStream_t stream) {
  const float* left  = (const float*)d_in[0];
  const float* right = (const float*)d_in[1];
  float* outp = (float*)d_out;
  cost_volume_mfma<<<dim3(B_ * H_ * 2), dim3(NT), 0, stream>>>(left, right, outp);
}

// Round 7
// 124.444 us; speedup vs baseline: 4.8540x; 4.8540x over previous
//
#include <hip/hip_runtime.h>
#include <hip/hip_bf16.h>

#define B_ 4
#define C_ 512
#define H_ 96
#define W_ 320
#define D_ 48
#define HW_ (H_*W_)

#define KC 32              // channels per chunk = MFMA K
#define NCHUNK (C_/KC)     // 16
#define LCOLS 160          // L columns per half-row
#define COLS 368           // 160 L + 208 R (48-col halo)
#define CSTR 72            // bytes per LDS column: 64B data + 8B pad (bank walk 18)
#define BUFB (COLS*CSTR)   // 26496 B per buffer -> 2 bufs = 52992 B -> 3 blocks/CU
#define NT 320             // 5 waves; grid 768 = 3 blocks/CU exactly
#define NC4 (COLS/4)       // 92 col-quad groups
#define NU (NC4*8)         // 736 staging units (c4, chq)
#define SIT 3              // ceil(736/320)
#define EPS 168            // epilogue row stride in floats

typedef __attribute__((ext_vector_type(8))) short bf16x8;
typedef __attribute__((ext_vector_type(4))) float f32x4;

__device__ __forceinline__ unsigned cvt2(float lo, float hi) {
  union { __hip_bfloat162 h2; unsigned u; } u;
  u.h2 = __float22bfloat162_rn(make_float2(lo, hi));   // v_cvt_pk_bf16_f32 (RNE)
  return u.u;
}
// LDS: column-major [col][k], stride 72 B, NO swizzle.
// 18*lc mod 32 bijects lc=0..15 onto the 16 even banks -> fragment reads
// (b64 pairs at col*72 + 16*lg, +8) are exactly at the 4-access/bank floor.
__device__ __forceinline__ int ldsoff(int col, int q) {   // q = 8B k-granule
  return col * CSTR + (q << 3);
}

// barrier WITHOUT vmcnt drain: ds ops flushed, global loads stay in flight
#define BAR() do { \
  asm volatile("s_waitcnt lgkmcnt(0)" ::: "memory"); \
  __builtin_amdgcn_sched_barrier(0); \
  __builtin_amdgcn_s_barrier(); \
  __builtin_amdgcn_sched_barrier(0); } while (0)

__global__ __launch_bounds__(NT, 4)   // VGPR <= 128: 3 blocks/CU co-resident
void cost_volume_mfma(const float* __restrict__ Lp,
                      const float* __restrict__ Rp,
                      float* __restrict__ out) {
  __shared__ __align__(16) char lds[2 * BUFB];   // 52992 B
  const int tid = threadIdx.x;
  const int bid = blockIdx.x;
  const int half = bid & 1;
  const int bh = bid >> 1;
  const int b = bh / H_, h = bh % H_;
  const int wv = tid >> 6;
  const int lc = tid & 15;
  const int lg = (tid >> 4) & 3;
  const int mh0 = 2 * wv;
  const int m0 = 10 * half + mh0;

  // ---- staging descriptors: u -> (c4 = u%92, chq = u/92) ----
  // consecutive lanes -> consecutive c4 -> each of the 4 dwordx4 loads is
  // 16 B/lane fully coalesced
  const float* sp[SIT];
  int dstb[SIT];
  bool sact[SIT];
#pragma unroll
  for (int it = 0; it < SIT; ++it) {
    const int u = tid + NT * it;
    bool a = (u < NU);
    const int uc = a ? u : 0;
    const int c4 = uc % NC4;
    const int chq = uc / NC4;
    const int col = 4 * c4;
    int x;
    const float* basep;
    if (col < LCOLS) { x = 160 * half + col; basep = Lp; }
    else             { x = 160 * half - 48 + (col - LCOLS); basep = Rp; a = a && (x >= 0); }
    if (x < 0) x = 0;
    sp[it] = basep + ((size_t)(b * C_ + 4 * chq) * H_ + h) * W_ + x;
    dstb[it] = ldsoff(col, chq);
    sact[it] = a;
  }

  float4 sreg[SIT][4];   // 4 channels x float4-of-x per unit (48 VGPR)

#define SLOAD() \
  _Pragma("unroll") for (int it = 0; it < SIT; ++it) { \
    if (sact[it]) { \
      _Pragma("unroll") for (int l = 0; l < 4; ++l) \
        sreg[it][l] = *(const float4*)(sp[it] + (size_t)l * HW_); \
    } \
    sp[it] += (size_t)KC * HW_; \
  }

  // col j of the quad: granule chq = bf16{ch0,ch1,ch2,ch3} (k ascending)
#define SWRITE(bb) \
  _Pragma("unroll") for (int it = 0; it < SIT; ++it) if (sact[it]) { \
    char* p = lds + (bb) * BUFB + dstb[it]; \
    uint2 v; \
    v.x = cvt2(sreg[it][0].x, sreg[it][1].x); v.y = cvt2(sreg[it][2].x, sreg[it][3].x); \
    *(uint2*)(p) = v; \
    v.x = cvt2(sreg[it][0].y, sreg[it][1].y); v.y = cvt2(sreg[it][2].y, sreg[it][3].y); \
    *(uint2*)(p + CSTR) = v; \
    v.x = cvt2(sreg[it][0].z, sreg[it][1].z); v.y = cvt2(sreg[it][2].z, sreg[it][3].z); \
    *(uint2*)(p + 2 * CSTR) = v; \
    v.x = cvt2(sreg[it][0].w, sreg[it][1].w); v.y = cvt2(sreg[it][2].w, sreg[it][3].w); \
    *(uint2*)(p + 3 * CSTR) = v; \
  }

  // ---- fragment byte offsets: lane (lc,lg) reads k = 8lg..8lg+7 of its col ----
  const int aoff0 = ldsoff(16 * mh0 + lc, 2 * lg);
  const int aoff1 = ldsoff(16 * (mh0 + 1) + lc, 2 * lg);
  int boff[5];
  bool bval[5];
#pragma unroll
  for (int dnp = 0; dnp < 5; ++dnp) {
    const int jn = m0 + 1 - dnp;
    const int jloc = jn - 10 * half;          // >= -3 -> LDS col >= 160
    boff[dnp] = ldsoff(208 + 16 * jloc + lc, 2 * lg);
    bval[dnp] = (jn >= 0);
  }

  union FragU { uint2 h[2]; bf16x8 v; };
#define FREAD(fr, base, off) do { FragU _f; \
  _f.h[0] = *(const uint2*)((base) + (off)); \
  _f.h[1] = *(const uint2*)((base) + (off) + 8); fr = _f.v; } while (0)

  f32x4 acc[2][4];
#pragma unroll
  for (int ml = 0; ml < 2; ++ml)
#pragma unroll
    for (int dn = 0; dn < 4; ++dn) acc[ml][dn] = (f32x4){0.f, 0.f, 0.f, 0.f};

  // ---- pipelined K loop: loads stay in flight across raw s_barrier ----
  SLOAD();             // chunk 0
  SWRITE(0);           // vmcnt wait here, ds_write buf0
  SLOAD();             // chunk 1 in flight across the barrier
  BAR();
#pragma unroll 2
  for (int k = 0; k < NCHUNK; ++k) {
    const char* base = lds + (k & 1) * BUFB;
    bf16x8 a0, a1;
    FREAD(a0, base, aoff0);
    FREAD(a1, base, aoff1);
    bf16x8 bf[5];
#pragma unroll
    for (int dnp = 0; dnp < 5; ++dnp)
      if (bval[dnp]) FREAD(bf[dnp], base, boff[dnp]);
#pragma unroll
    for (int dn = 0; dn < 4; ++dn) {
      if (bval[dn + 1])
        acc[0][dn] = __builtin_amdgcn_mfma_f32_16x16x32_bf16(a0, bf[dn + 1], acc[0][dn], 0, 0, 0);
      if (bval[dn])
        acc[1][dn] = __builtin_amdgcn_mfma_f32_16x16x32_bf16(a1, bf[dn], acc[1][dn], 0, 0, 0);
    }
    if (k < NCHUNK - 1) {
      SWRITE((k + 1) & 1);          // vmcnt wait: loads issued one full chunk ago
      if (k < NCHUNK - 2) SLOAD();  // chunk k+2 into freed regs
      BAR();
    }
  }

  // ---- epilogue: transpose through LDS -> coalesced stores ----
  __syncthreads();
  float* ep = (float*)lds;                   // [48][EPS] = 32256 B, reuse
#pragma unroll
  for (int e = 0; e < (D_ * EPS + NT - 1) / NT; ++e) {
    const int i = tid + NT * e;
    if (i < D_ * EPS) ep[i] = 0.f;
  }
  __syncthreads();
  const float scale = 1.f / 512.f;
#pragma unroll
  for (int ml = 0; ml < 2; ++ml) {
    const int mh = mh0 + ml;
#pragma unroll
    for (int dn = 0; dn < 4; ++dn) {
      const int jn = m0 + ml - dn;
      if (jn >= 0) {
#pragma unroll
        for (int q = 0; q < 4; ++q) {
          const int i = 4 * lg + q;          // C/D row = 4*(lane>>4) + reg
          const int d = 16 * dn + i - lc;    // d = w - w'
          if (d >= 0 && d < D_)
            ep[d * EPS + 16 * mh + i] = acc[ml][dn][q] * scale;
        }
      }
    }
  }
  __syncthreads();
#pragma unroll
  for (int e = 0; e < 6; ++e) {
    const int u = tid + NT * e;
    const int d = u / 40, c4 = u % 40;
    const float4 v = *(const float4*)(ep + d * EPS + 4 * c4);
    float* o = out + (((size_t)b * D_ + d) * H_ + h) * W_ + 160 * half + 4 * c4;
    *(float4*)o = v;
  }
}

extern "C" void kernel_launch(void* const* d_in, const int* in_sizes, int n_in,
                              void* d_out, int out_size, void* d_ws, size_t ws_size,
                              hipStream_t stream) {
  const float* left  = (const float*)d_in[0];
  const float* right = (const float*)d_in[1];
  float* outp = (float*)d_out;
  cost_volume_mfma<<<dim3(B_ * H_ * 2), dim3(NT), 0, stream>>>(left, right, outp);
}